// Round 10
// baseline (291.548 us; speedup 1.0000x reference)
//
#include <hip/hip_runtime.h>
#include <math.h>

#define N_NODES 8192
#define D_FEAT  512
#define DEG     16
#define E_EDGES (N_NODES * DEG)
#define FEAT_W  576      // 544 used (8*(64+4)) + 32 zero-pad for K%64==0
#define FEAT_USED 544
#define OUT_W   512
#define QKV_W   1536     // 512 q | 512 k | 512 v   (qv separate, fp32)

typedef unsigned short u16;
typedef __attribute__((ext_vector_type(8))) short short8;   // 8 bf16 for MFMA
typedef __attribute__((ext_vector_type(8))) unsigned short us8;
typedef __attribute__((ext_vector_type(4))) float f32x4;

// ---- bf16 helpers (RNE) ----------------------------------------------------
__device__ __forceinline__ u16 f2bf(float f) {
    union { float f; unsigned u; } c; c.f = f;
    unsigned u = c.u;
    unsigned r = u + 0x7FFFu + ((u >> 16) & 1u);
    return (u16)(r >> 16);
}
__device__ __forceinline__ float bf2f(u16 h) {
    union { unsigned u; float f; } c; c.u = ((unsigned)h) << 16;
    return c.f;
}

// ---- async global->LDS 16B (lds dest = wave-uniform base + lane*16) --------
__device__ __forceinline__ void async16(const void* g, void* l) {
    __builtin_amdgcn_global_load_lds(
        (const __attribute__((address_space(1))) void*)g,
        (__attribute__((address_space(3))) void*)l, 16, 0, 0);
}

// ---------------------------------------------------------------------------
// qkv GEMM: qkv[8192,1536] = xh[8192,512] * Bfuse[1536,512]^T, bf16 in/out.
// BK=64, 128x128 tiles, 4 waves, grid 768 = 64 Mtiles x 12 Ntiles
// == EXACTLY 3 blocks/CU (no tail wave). XCD-swizzled: flat%8 keys the XCD;
// all N-tiles of an M-tile share an XCD (A panel L2-resident).
// LDS [128][64] u16/matrix; 16B-chunk XOR-swizzle by (row&7) on the global
// source address (global_load_lds dest is fixed base+lane*16).
// ---------------------------------------------------------------------------
__global__ __launch_bounds__(256) void gemm_qkv(
    const u16* __restrict__ xh, const u16* __restrict__ Bfuse,
    u16* __restrict__ qkv)
{
    __shared__ u16 smem[128 * 64 * 2];   // 32 KB
    u16* sA = smem;
    u16* sB = smem + 128 * 64;

    const int tid = threadIdx.x;
    const int flat = blockIdx.x;
    const int xcd = flat & 7;
    const int rr  = flat >> 3;                  // 0..95
    const int bm  = (xcd + 8 * (rr / 12)) * 128;
    const int bn  = (rr % 12) * 128;

    const int wave = tid >> 6;
    const int lane = tid & 63;
    const int wr   = (wave >> 1) * 64;
    const int wc   = (wave & 1) * 64;
    const int lrow = lane & 15;
    const int quad = lane >> 4;

    f32x4 acc[4][4];
    #pragma unroll
    for (int i = 0; i < 4; ++i)
        #pragma unroll
        for (int j = 0; j < 4; ++j) {
            f32x4 z = {0.f, 0.f, 0.f, 0.f};
            acc[i][j] = z;
        }

    for (int k0 = 0; k0 < 512; k0 += 64) {
        #pragma unroll
        for (int i = 0; i < 4; ++i) {
            const int lin = i * 256 + tid;            // 1024 chunks/matrix
            const int row = lin >> 3;
            const int seg = ((lin & 7) ^ (row & 7)) << 3;
            async16(xh    + (size_t)(bm + row) * 512 + k0 + seg, sA + (lin << 3));
            async16(Bfuse + (size_t)(bn + row) * 512 + k0 + seg, sB + (lin << 3));
        }
        __syncthreads();

        #pragma unroll
        for (int ko = 0; ko < 64; ko += 32) {
            const int cbase = ko >> 3;
            short8 a_h[4], b_h[4];
            #pragma unroll
            for (int t = 0; t < 4; ++t) {
                const int ra = wr + t * 16 + lrow;
                const int rb = wc + t * 16 + lrow;
                a_h[t] = *(const short8*)&sA[ra * 64 + (((cbase + quad) ^ (ra & 7)) << 3)];
                b_h[t] = *(const short8*)&sB[rb * 64 + (((cbase + quad) ^ (rb & 7)) << 3)];
            }
            #pragma unroll
            for (int mt = 0; mt < 4; ++mt)
                #pragma unroll
                for (int nt = 0; nt < 4; ++nt)
                    acc[mt][nt] = __builtin_amdgcn_mfma_f32_16x16x32_bf16(
                        a_h[mt], b_h[nt], acc[mt][nt], 0, 0, 0);
        }
        __syncthreads();
    }

    // C/D layout: col = lane&15, row = quad*4 + r
    #pragma unroll
    for (int nt = 0; nt < 4; ++nt) {
        const int col = bn + wc + nt * 16 + lrow;
        #pragma unroll
        for (int mt = 0; mt < 4; ++mt)
            #pragma unroll
            for (int r = 0; r < 4; ++r) {
                const int row = bm + wr + mt * 16 + quad * 4 + r;
                qkv[(size_t)row * QKV_W + col] = f2bf(acc[mt][nt][r]);
            }
    }
}

// ---------------------------------------------------------------------------
// Out GEMM: out[8192,512] = feat[8192,576] * Woth[512,576]^T + bout.
// 64x128 tiles (M x N), BK=64, grid 512 = 128 Mtiles x 4 Ntiles = 2/CU.
// Wave computes 32x64 (acc[2][4]). LDS: A 64x64 (8 KB) + B 128x64 (16 KB).
// ---------------------------------------------------------------------------
__global__ __launch_bounds__(256) void gemm_out(
    const u16* __restrict__ feat, const u16* __restrict__ Woth,
    const float* __restrict__ bout, float* __restrict__ out)
{
    __shared__ u16 smem[64 * 64 + 128 * 64];   // 24 KB
    u16* sA = smem;
    u16* sB = smem + 64 * 64;

    const int tid = threadIdx.x;
    const int flat = blockIdx.x;
    const int xcd = flat & 7;
    const int rr  = flat >> 3;                  // 0..63
    const int bm  = (xcd + 8 * (rr / 4)) * 64;  // 128 M-tiles of 64 rows
    const int bn  = (rr % 4) * 128;

    const int wave = tid >> 6;
    const int lane = tid & 63;
    const int wr   = (wave >> 1) * 32;
    const int wc   = (wave & 1) * 64;
    const int lrow = lane & 15;
    const int quad = lane >> 4;

    f32x4 acc[2][4];
    #pragma unroll
    for (int i = 0; i < 2; ++i)
        #pragma unroll
        for (int j = 0; j < 4; ++j) {
            f32x4 z = {0.f, 0.f, 0.f, 0.f};
            acc[i][j] = z;
        }

    for (int k0 = 0; k0 < FEAT_W; k0 += 64) {
        #pragma unroll
        for (int i = 0; i < 2; ++i) {             // A: 512 chunks
            const int lin = i * 256 + tid;
            const int row = lin >> 3;
            const int seg = ((lin & 7) ^ (row & 7)) << 3;
            async16(feat + (size_t)(bm + row) * FEAT_W + k0 + seg, sA + (lin << 3));
        }
        #pragma unroll
        for (int i = 0; i < 4; ++i) {             // B: 1024 chunks
            const int lin = i * 256 + tid;
            const int row = lin >> 3;
            const int seg = ((lin & 7) ^ (row & 7)) << 3;
            async16(Woth + (size_t)(bn + row) * FEAT_W + k0 + seg, sB + (lin << 3));
        }
        __syncthreads();

        #pragma unroll
        for (int ko = 0; ko < 64; ko += 32) {
            const int cbase = ko >> 3;
            short8 a_h[2], b_h[4];
            #pragma unroll
            for (int t = 0; t < 2; ++t) {
                const int ra = wr + t * 16 + lrow;
                a_h[t] = *(const short8*)&sA[ra * 64 + (((cbase + quad) ^ (ra & 7)) << 3)];
            }
            #pragma unroll
            for (int t = 0; t < 4; ++t) {
                const int rb = wc + t * 16 + lrow;
                b_h[t] = *(const short8*)&sB[rb * 64 + (((cbase + quad) ^ (rb & 7)) << 3)];
            }
            #pragma unroll
            for (int mt = 0; mt < 2; ++mt)
                #pragma unroll
                for (int nt = 0; nt < 4; ++nt)
                    acc[mt][nt] = __builtin_amdgcn_mfma_f32_16x16x32_bf16(
                        a_h[mt], b_h[nt], acc[mt][nt], 0, 0, 0);
        }
        __syncthreads();
    }

    #pragma unroll
    for (int nt = 0; nt < 4; ++nt) {
        const int col = bn + wc + nt * 16 + lrow;
        const float bb = bout[col];
        #pragma unroll
        for (int mt = 0; mt < 2; ++mt)
            #pragma unroll
            for (int r = 0; r < 4; ++r) {
                const int row = bm + wr + mt * 16 + quad * 4 + r;
                out[(size_t)row * OUT_W + col] = acc[mt][nt][r] + bb;
            }
    }
}

// ---------------------------------------------------------------------------
// Fused prep: block-range partition over four jobs.
//  [0, 4096)      : x fp32 -> bf16 xh                  (1048576 ushort4)
//  [4096, 4864)   : Bfuse [1536,512] bf16 (Wq*s|Wk|Wv) (196608 ushort4)
//  [4864, 5152)   : Woth [512,576] bf16, zero pad      (73728 ushort4)
//  [5152, 5920)   : qv_all [8192,24] fp32 dots         (196608 threads)
// ---------------------------------------------------------------------------
__global__ __launch_bounds__(256) void prep_kernel(
    const float* __restrict__ x,
    const float* __restrict__ Wq, const float* __restrict__ Wk,
    const float* __restrict__ Wv, const float* __restrict__ Wqv,
    const float* __restrict__ Wout,
    u16* __restrict__ xh, u16* __restrict__ B, u16* __restrict__ Woth,
    float* __restrict__ qv_all)
{
    const int b = blockIdx.x;
    const int tid = threadIdx.x;
    if (b < 4096) {
        const int i = b * 256 + tid;
        const float4 v = ((const float4*)x)[i];
        ushort4 h;
        h.x = f2bf(v.x); h.y = f2bf(v.y); h.z = f2bf(v.z); h.w = f2bf(v.w);
        ((ushort4*)xh)[i] = h;
    } else if (b < 4864) {
        const int idx = (b - 4096) * 256 + tid;      // < 196608
        const int row = idx >> 7;                    // 0..1535
        const int c4  = idx & 127;
        const float* src; float scale = 1.f;
        if (row < 512)       { src = Wq + (size_t)row * 512; scale = 0.125f; }
        else if (row < 1024) { src = Wk + (size_t)(row - 512) * 512; }
        else                 { src = Wv + (size_t)(row - 1024) * 512; }
        const float4 v = *(const float4*)(src + c4 * 4);
        ushort4 h;
        h.x = f2bf(v.x * scale); h.y = f2bf(v.y * scale);
        h.z = f2bf(v.z * scale); h.w = f2bf(v.w * scale);
        ((ushort4*)B)[idx] = h;
    } else if (b < 5152) {
        const int i = (b - 4864) * 256 + tid;        // < 73728 exact
        const int row = i / (FEAT_W / 4);            // /144
        const int c4  = i % (FEAT_W / 4);
        float4 v = make_float4(0.f, 0.f, 0.f, 0.f);
        if (c4 < FEAT_USED / 4)
            v = *(const float4*)(Wout + (size_t)row * FEAT_USED + c4 * 4);
        ushort4 h;
        h.x = f2bf(v.x); h.y = f2bf(v.y); h.z = f2bf(v.z); h.w = f2bf(v.w);
        ((ushort4*)Woth)[i] = h;
    } else {
        const int t = (b - 5152) * 256 + tid;        // < 196608 exact
        const int n = t / 24;
        const int c = t % 24;
        const float4* xr = (const float4*)(x + (size_t)n * 512);
        const float4* wr = (const float4*)(Wqv + (size_t)c * 512);
        float acc = 0.f;
        #pragma unroll 4
        for (int k = 0; k < 128; ++k) {
            const float4 a = xr[k], w = wr[k];
            acc += a.x * w.x + a.y * w.y + a.z * w.z + a.w * w.w;
        }
        qv_all[t] = acc;
    }
}

// ---------------------------------------------------------------------------
// Edge stage (R5/R7 proven config): ONE WAVE PER NODE, two-pass with LDS
// v-staging. lane = h*8+sub owns dims [lane*8, lane*8+8) of the 512-dim row.
// ---------------------------------------------------------------------------
#define EK_WAVES 2   // 16 KB LDS per wave; 32 KB/block
__global__ __launch_bounds__(EK_WAVES * 64) void edge_kernel(
    const u16* __restrict__ qkv,        // [N, 1536] bf16
    const float* __restrict__ qv_all,   // [N, 24] fp32
    const int* __restrict__ col_index, const int* __restrict__ to_col,
    const float* __restrict__ att_bias, const float* __restrict__ dist,
    const float* __restrict__ pos, const float* __restrict__ col_pos,
    u16* __restrict__ feat)             // [N, 576] bf16 (544 used)
{
    __shared__ u16 vbuf[EK_WAVES * DEG * 512];

    const int wave = threadIdx.x >> 6;
    const int lane = threadIdx.x & 63;
    const int n = blockIdx.x * EK_WAVES + wave;
    const int h = lane >> 3;
    const int sub = lane & 7;

    const size_t qbase = (size_t)n * QKV_W;
    const int hoff = lane * 8;            // == h*64 + sub*8

    float qf[8];
    {
        const us8 qu = *(const us8*)(qkv + qbase + hoff);
        #pragma unroll
        for (int i = 0; i < 8; ++i) qf[i] = bf2f(qu[i]);
    }
    float qv0, qv1, qv2;
    {
        const float qvl = qv_all[n * 24 + (lane < 24 ? lane : 0)];
        qv0 = __shfl(qvl, h * 3 + 0);
        qv1 = __shfl(qvl, h * 3 + 1);
        qv2 = __shfl(qvl, h * 3 + 2);
    }
    const float px = pos[3 * n + 0], py = pos[3 * n + 1], pz = pos[3 * n + 2];

    const int j16 = lane & 15;
    const int e0  = n * DEG + j16;
    const int c_l  = col_index[e0];
    const int cc_l = to_col[c_l];
    const float d_l = dist[e0];
    const float invd_l = (d_l == 0.f) ? 0.f : (1.f / d_l);
    const float rx_l = col_pos[3 * c_l + 0] - px;
    const float ry_l = col_pos[3 * c_l + 1] - py;
    const float rz_l = col_pos[3 * c_l + 2] - pz;

    const float b0 = att_bias[(size_t)h * E_EDGES + n * DEG + sub * 2 + 0];
    const float b1 = att_bias[(size_t)h * E_EDGES + n * DEG + sub * 2 + 1];

    float logit[DEG];
    u16* vb = &vbuf[wave * DEG * 512];
    #pragma unroll
    for (int j = 0; j < DEG; ++j) {
        const int cc = __shfl(cc_l, j);
        const u16* rowp = qkv + (size_t)cc * QKV_W + hoff;
        async16(rowp + 1024, vb + j * 512);          // v row -> LDS
        const us8 ku = *(const us8*)(rowp + 512);    // k row -> regs
        float dot = 0.f;
        #pragma unroll
        for (int i = 0; i < 8; ++i) dot += qf[i] * bf2f(ku[i]);
        dot += __shfl_xor(dot, 1, 8);
        dot += __shfl_xor(dot, 2, 8);
        dot += __shfl_xor(dot, 4, 8);
        const float invd = __shfl(invd_l, j);
        const float ang = qv0 * __shfl(rx_l, j) + qv1 * __shfl(ry_l, j)
                        + qv2 * __shfl(rz_l, j);
        const float bj = __shfl((j & 1) ? b1 : b0, j >> 1, 8);
        logit[j] = dot + bj + ang * invd;
    }

    float m = logit[0];
    #pragma unroll
    for (int j = 1; j < DEG; ++j) m = fmaxf(m, logit[j]);
    float s = 0.f;
    #pragma unroll
    for (int j = 0; j < DEG; ++j) { logit[j] = __expf(logit[j] - m); s += logit[j]; }
    const float inv_s = 1.f / s;

    __syncthreads();   // drain global_load_lds + make LDS visible

    float y[8] = {0.f, 0.f, 0.f, 0.f, 0.f, 0.f, 0.f, 0.f};
    float dx = 0.f, dy = 0.f, dz = 0.f, aid = 0.f;
    #pragma unroll
    for (int j = 0; j < DEG; ++j) {
        const float a = logit[j] * inv_s;
        const us8 vu = *(const us8*)&vb[j * 512 + hoff];
        #pragma unroll
        for (int i = 0; i < 8; ++i) y[i] += a * bf2f(vu[i]);
        const float na = a * __shfl(invd_l, j);
        dx += na * __shfl(rx_l, j);
        dy += na * __shfl(ry_l, j);
        dz += na * __shfl(rz_l, j);
        aid += na;
    }

    u16* f = feat + (size_t)n * FEAT_W + h * 68;
    ushort4 o0, o1;
    o0.x = f2bf(y[0]); o0.y = f2bf(y[1]); o0.z = f2bf(y[2]); o0.w = f2bf(y[3]);
    o1.x = f2bf(y[4]); o1.y = f2bf(y[5]); o1.z = f2bf(y[6]); o1.w = f2bf(y[7]);
    *(ushort4*)(f + sub * 8 + 0) = o0;
    *(ushort4*)(f + sub * 8 + 4) = o1;
    if (sub == 0) {
        const float nrm = sqrtf(dx * dx + dy * dy + dz * dz);
        const float rn = 1.f / fmaxf(nrm, 1e-12f);
        ushort4 ex;
        ex.x = f2bf(dx * rn); ex.y = f2bf(dy * rn);
        ex.z = f2bf(dz * rn); ex.w = f2bf(aid);
        *(ushort4*)(f + 64) = ex;
    }
}

// ---------------------------------------------------------------------------
extern "C" void kernel_launch(void* const* d_in, const int* in_sizes, int n_in,
                              void* d_out, int out_size, void* d_ws, size_t ws_size,
                              hipStream_t stream)
{
    const float* x         = (const float*)d_in[0];
    const int*   col_index = (const int*)d_in[2];
    const int*   to_col    = (const int*)d_in[3];
    const float* att_bias  = (const float*)d_in[4];
    const float* dist      = (const float*)d_in[5];
    const float* pos       = (const float*)d_in[6];
    const float* col_pos   = (const float*)d_in[7];
    const float* Wq        = (const float*)d_in[8];
    const float* Wqv       = (const float*)d_in[9];
    const float* Wk        = (const float*)d_in[10];
    const float* Wv        = (const float*)d_in[11];
    const float* Wout      = (const float*)d_in[12];
    const float* bout      = (const float*)d_in[13];
    float* out = (float*)d_out;

    // Workspace layout (bytes), total ~45.9 MB
    char* ws = (char*)d_ws;
    u16*   qkv    = (u16*)(ws + 0);            // [8192,1536] bf16  25,165,824
    u16*   xh     = (u16*)(ws + 25165824);     // [8192,512]  bf16   8,388,608
    u16*   Bfuse  = (u16*)(ws + 33554432);     // [1536,512]  bf16   1,572,864
    u16*   Woth   = (u16*)(ws + 35127296);     // [512,576]   bf16     589,824
    float* qv_all = (float*)(ws + 35717120);   // [8192,24]   fp32     786,432
    u16*   feat   = (u16*)(ws + 36503552);     // [8192,576]  bf16   9,437,184

    dim3 blk(256);

    // 0) prep: x->bf16, Bfuse, Woth, qv fp32
    hipLaunchKernelGGL(prep_kernel, dim3(5920), blk, 0, stream,
                       x, Wq, Wk, Wv, Wqv, Wout, xh, Bfuse, Woth, qv_all);

    // 1) qkv = xh * Bfuse^T  (grid 768 == 3 blocks/CU, zero tail)
    hipLaunchKernelGGL(gemm_qkv, dim3(768), blk, 0, stream, xh, Bfuse, qkv);

    // 2) edge: wave per node, two-pass + LDS v-staging
    hipLaunchKernelGGL(edge_kernel, dim3(N_NODES / EK_WAVES), dim3(EK_WAVES * 64),
                       0, stream,
                       qkv, qv_all, col_index, to_col, att_bias, dist, pos,
                       col_pos, feat);

    // 3) out = feat * Woth^T + bout  (64x128 tiles, grid 512 = 2/CU)
    hipLaunchKernelGGL(gemm_out, dim3(512), blk, 0, stream,
                       feat, Woth, bout, out);
}

// Round 11
// 167.268 us; speedup vs baseline: 1.7430x; 1.7430x over previous
//
#include <hip/hip_runtime.h>
#include <math.h>

#define N_NODES 8192
#define D_FEAT  512
#define DEG     16
#define E_EDGES (N_NODES * DEG)
#define FEAT_W  576      // 544 used (8*(64+4)) + 32 zero-pad for K%64==0
#define FEAT_USED 544
#define OUT_W   512
#define QKV_W   1664     // 512 q | 512 k | 512 v | 24 qv | 104 pad  (13*128)

typedef unsigned short u16;
typedef __attribute__((ext_vector_type(8))) short short8;   // 8 bf16 for MFMA
typedef __attribute__((ext_vector_type(8))) unsigned short us8;
typedef __attribute__((ext_vector_type(4))) float f32x4;

// ---- bf16 helpers (RNE) ----------------------------------------------------
__device__ __forceinline__ u16 f2bf(float f) {
    union { float f; unsigned u; } c; c.f = f;
    unsigned u = c.u;
    unsigned r = u + 0x7FFFu + ((u >> 16) & 1u);
    return (u16)(r >> 16);
}
__device__ __forceinline__ float bf2f(u16 h) {
    union { unsigned u; float f; } c; c.u = ((unsigned)h) << 16;
    return c.f;
}

// ---- async global->LDS 16B (lds dest = wave-uniform base + lane*16) --------
__device__ __forceinline__ void async16(const void* g, void* l) {
    __builtin_amdgcn_global_load_lds(
        (const __attribute__((address_space(1))) void*)g,
        (__attribute__((address_space(3))) void*)l, 16, 0, 0);
}

// ---------------------------------------------------------------------------
// qkv GEMM: qkv[8192,1664] = xh[8192,512] * Bfuse[1664,512]^T, bf16 in/out.
// BK=64, 128x128 tiles, 4 waves, grid 832 = 64 Mtiles x 13 Ntiles,
// XCD-swizzled (flat%8 keys the XCD; all N-tiles of an M-tile share an XCD
// so the A panel stays L2-resident). R7-proven configuration.
// LDS [128][64] u16/matrix; 16B-chunk XOR-swizzle by (row&7) applied to the
// global source address (global_load_lds dest is fixed base+lane*16).
// ---------------------------------------------------------------------------
__global__ __launch_bounds__(256) void gemm_qkv(
    const u16* __restrict__ xh, const u16* __restrict__ Bfuse,
    u16* __restrict__ qkv)
{
    __shared__ u16 smem[128 * 64 * 2];   // 32 KB
    u16* sA = smem;
    u16* sB = smem + 128 * 64;

    const int tid = threadIdx.x;
    const int flat = blockIdx.x;
    const int xcd = flat & 7;
    const int rr  = flat >> 3;                  // 0..103
    const int bm  = (xcd + 8 * (rr / 13)) * 128;
    const int bn  = (rr % 13) * 128;

    const int wave = tid >> 6;
    const int lane = tid & 63;
    const int wr   = (wave >> 1) * 64;
    const int wc   = (wave & 1) * 64;
    const int lrow = lane & 15;
    const int quad = lane >> 4;

    f32x4 acc[4][4];
    #pragma unroll
    for (int i = 0; i < 4; ++i)
        #pragma unroll
        for (int j = 0; j < 4; ++j) {
            f32x4 z = {0.f, 0.f, 0.f, 0.f};
            acc[i][j] = z;
        }

    for (int k0 = 0; k0 < 512; k0 += 64) {
        #pragma unroll
        for (int i = 0; i < 4; ++i) {
            const int lin = i * 256 + tid;            // 1024 chunks/matrix
            const int row = lin >> 3;
            const int seg = ((lin & 7) ^ (row & 7)) << 3;
            async16(xh    + (size_t)(bm + row) * 512 + k0 + seg, sA + (lin << 3));
            async16(Bfuse + (size_t)(bn + row) * 512 + k0 + seg, sB + (lin << 3));
        }
        __syncthreads();

        #pragma unroll
        for (int ko = 0; ko < 64; ko += 32) {
            const int cbase = ko >> 3;
            short8 a_h[4], b_h[4];
            #pragma unroll
            for (int t = 0; t < 4; ++t) {
                const int ra = wr + t * 16 + lrow;
                const int rb = wc + t * 16 + lrow;
                a_h[t] = *(const short8*)&sA[ra * 64 + (((cbase + quad) ^ (ra & 7)) << 3)];
                b_h[t] = *(const short8*)&sB[rb * 64 + (((cbase + quad) ^ (rb & 7)) << 3)];
            }
            #pragma unroll
            for (int mt = 0; mt < 4; ++mt)
                #pragma unroll
                for (int nt = 0; nt < 4; ++nt)
                    acc[mt][nt] = __builtin_amdgcn_mfma_f32_16x16x32_bf16(
                        a_h[mt], b_h[nt], acc[mt][nt], 0, 0, 0);
        }
        __syncthreads();
    }

    // C/D layout: col = lane&15, row = quad*4 + r
    #pragma unroll
    for (int nt = 0; nt < 4; ++nt) {
        const int col = bn + wc + nt * 16 + lrow;
        #pragma unroll
        for (int mt = 0; mt < 4; ++mt)
            #pragma unroll
            for (int r = 0; r < 4; ++r) {
                const int row = bm + wr + mt * 16 + quad * 4 + r;
                qkv[(size_t)row * QKV_W + col] = f2bf(acc[mt][nt][r]);
            }
    }
}

// ---------------------------------------------------------------------------
// Out GEMM: out[8192,512] = feat[8192,576] * Woth[512,576]^T + bout.
// 64x128 tiles (M x N), BK=64, grid 512 = 128 Mtiles x 4 Ntiles = 2
// blocks/CU (vs 1/CU for the 128x128 tiling). Wave computes 32x64
// (acc[2][4]). LDS: A 64x64 (8 KB) + B 128x64 (16 KB) = 24 KB.
// ---------------------------------------------------------------------------
__global__ __launch_bounds__(256) void gemm_out(
    const u16* __restrict__ feat, const u16* __restrict__ Woth,
    const float* __restrict__ bout, float* __restrict__ out)
{
    __shared__ u16 smem[64 * 64 + 128 * 64];   // 24 KB
    u16* sA = smem;
    u16* sB = smem + 64 * 64;

    const int tid = threadIdx.x;
    const int flat = blockIdx.x;
    const int xcd = flat & 7;
    const int rr  = flat >> 3;                  // 0..63
    const int bm  = (xcd + 8 * (rr / 4)) * 64;  // 128 M-tiles of 64 rows
    const int bn  = (rr % 4) * 128;

    const int wave = tid >> 6;
    const int lane = tid & 63;
    const int wr   = (wave >> 1) * 32;
    const int wc   = (wave & 1) * 64;
    const int lrow = lane & 15;
    const int quad = lane >> 4;

    f32x4 acc[2][4];
    #pragma unroll
    for (int i = 0; i < 2; ++i)
        #pragma unroll
        for (int j = 0; j < 4; ++j) {
            f32x4 z = {0.f, 0.f, 0.f, 0.f};
            acc[i][j] = z;
        }

    for (int k0 = 0; k0 < FEAT_W; k0 += 64) {
        #pragma unroll
        for (int i = 0; i < 2; ++i) {             // A: 512 chunks
            const int lin = i * 256 + tid;
            const int row = lin >> 3;
            const int seg = ((lin & 7) ^ (row & 7)) << 3;
            async16(feat + (size_t)(bm + row) * FEAT_W + k0 + seg, sA + (lin << 3));
        }
        #pragma unroll
        for (int i = 0; i < 4; ++i) {             // B: 1024 chunks
            const int lin = i * 256 + tid;
            const int row = lin >> 3;
            const int seg = ((lin & 7) ^ (row & 7)) << 3;
            async16(Woth + (size_t)(bn + row) * FEAT_W + k0 + seg, sB + (lin << 3));
        }
        __syncthreads();

        #pragma unroll
        for (int ko = 0; ko < 64; ko += 32) {
            const int cbase = ko >> 3;
            short8 a_h[2], b_h[4];
            #pragma unroll
            for (int t = 0; t < 2; ++t) {
                const int ra = wr + t * 16 + lrow;
                a_h[t] = *(const short8*)&sA[ra * 64 + (((cbase + quad) ^ (ra & 7)) << 3)];
            }
            #pragma unroll
            for (int t = 0; t < 4; ++t) {
                const int rb = wc + t * 16 + lrow;
                b_h[t] = *(const short8*)&sB[rb * 64 + (((cbase + quad) ^ (rb & 7)) << 3)];
            }
            #pragma unroll
            for (int mt = 0; mt < 2; ++mt)
                #pragma unroll
                for (int nt = 0; nt < 4; ++nt)
                    acc[mt][nt] = __builtin_amdgcn_mfma_f32_16x16x32_bf16(
                        a_h[mt], b_h[nt], acc[mt][nt], 0, 0, 0);
        }
        __syncthreads();
    }

    #pragma unroll
    for (int nt = 0; nt < 4; ++nt) {
        const int col = bn + wc + nt * 16 + lrow;
        const float bb = bout[col];
        #pragma unroll
        for (int mt = 0; mt < 2; ++mt)
            #pragma unroll
            for (int r = 0; r < 4; ++r) {
                const int row = bm + wr + mt * 16 + quad * 4 + r;
                out[(size_t)row * OUT_W + col] = acc[mt][nt][r] + bb;
            }
    }
}

// ---------------------------------------------------------------------------
// Fused prep (R7-proven): block-range partition over three jobs.
//  [0, 4096)    : x fp32 -> bf16 xh                    (1048576 ushort4)
//  [4096, 4928) : Bfuse [1664,512] bf16 (Wq*s|Wk|Wv|Wqv|0) (212992 ushort4)
//  [4928, 5216) : Woth [512,576] bf16, zero pad        (73728 ushort4)
// ---------------------------------------------------------------------------
__global__ __launch_bounds__(256) void prep_kernel(
    const float* __restrict__ x,
    const float* __restrict__ Wq, const float* __restrict__ Wk,
    const float* __restrict__ Wv, const float* __restrict__ Wqv,
    const float* __restrict__ Wout,
    u16* __restrict__ xh, u16* __restrict__ B, u16* __restrict__ Woth)
{
    const int b = blockIdx.x;
    const int tid = threadIdx.x;
    if (b < 4096) {
        const int i = b * 256 + tid;
        const float4 v = ((const float4*)x)[i];
        ushort4 h;
        h.x = f2bf(v.x); h.y = f2bf(v.y); h.z = f2bf(v.z); h.w = f2bf(v.w);
        ((ushort4*)xh)[i] = h;
    } else if (b < 4928) {
        const int idx = (b - 4096) * 256 + tid;      // < 212992
        const int row = idx >> 7;                    // 0..1663
        const int c4  = idx & 127;
        float4 v = make_float4(0.f, 0.f, 0.f, 0.f);
        float scale = 1.f;
        if (row < 512) {
            v = *(const float4*)(Wq + (size_t)row * 512 + c4 * 4);
            scale = 0.125f;                          // 1/sqrt(64) folded into Wq
        } else if (row < 1024) {
            v = *(const float4*)(Wk + (size_t)(row - 512) * 512 + c4 * 4);
        } else if (row < 1536) {
            v = *(const float4*)(Wv + (size_t)(row - 1024) * 512 + c4 * 4);
        } else if (row < 1560) {
            v = *(const float4*)(Wqv + (size_t)(row - 1536) * 512 + c4 * 4);
        }
        ushort4 h;
        h.x = f2bf(v.x * scale); h.y = f2bf(v.y * scale);
        h.z = f2bf(v.z * scale); h.w = f2bf(v.w * scale);
        ((ushort4*)B)[idx] = h;
    } else {
        const int i = (b - 4928) * 256 + tid;        // < 73728 exact
        const int row = i / (FEAT_W / 4);            // /144
        const int c4  = i % (FEAT_W / 4);
        float4 v = make_float4(0.f, 0.f, 0.f, 0.f);
        if (c4 < FEAT_USED / 4)
            v = *(const float4*)(Wout + (size_t)row * FEAT_USED + c4 * 4);
        ushort4 h;
        h.x = f2bf(v.x); h.y = f2bf(v.y); h.z = f2bf(v.z); h.w = f2bf(v.w);
        ((ushort4*)Woth)[i] = h;
    }
}

// ---------------------------------------------------------------------------
// Edge stage (R5/R7 proven config): ONE WAVE PER NODE, two-pass with LDS
// v-staging. lane = h*8+sub owns dims [lane*8, lane*8+8) of the 512-dim row.
// ---------------------------------------------------------------------------
#define EK_WAVES 2   // 16 KB LDS per wave; 32 KB/block
__global__ __launch_bounds__(EK_WAVES * 64) void edge_kernel(
    const u16* __restrict__ qkv,        // [N, 1664] bf16
    const int* __restrict__ col_index, const int* __restrict__ to_col,
    const float* __restrict__ att_bias, const float* __restrict__ dist,
    const float* __restrict__ pos, const float* __restrict__ col_pos,
    u16* __restrict__ feat)             // [N, 576] bf16 (544 used)
{
    __shared__ u16 vbuf[EK_WAVES * DEG * 512];

    const int wave = threadIdx.x >> 6;
    const int lane = threadIdx.x & 63;
    const int n = blockIdx.x * EK_WAVES + wave;
    const int h = lane >> 3;
    const int sub = lane & 7;

    const size_t qbase = (size_t)n * QKV_W;
    const int hoff = lane * 8;            // == h*64 + sub*8

    float qf[8];
    {
        const us8 qu = *(const us8*)(qkv + qbase + hoff);
        #pragma unroll
        for (int i = 0; i < 8; ++i) qf[i] = bf2f(qu[i]);
    }
    float qv0, qv1, qv2;
    {
        const float qvl = bf2f(qkv[qbase + 1536 + (lane < 24 ? lane : 0)]);
        qv0 = __shfl(qvl, h * 3 + 0);
        qv1 = __shfl(qvl, h * 3 + 1);
        qv2 = __shfl(qvl, h * 3 + 2);
    }
    const float px = pos[3 * n + 0], py = pos[3 * n + 1], pz = pos[3 * n + 2];

    const int j16 = lane & 15;
    const int e0  = n * DEG + j16;
    const int c_l  = col_index[e0];
    const int cc_l = to_col[c_l];
    const float d_l = dist[e0];
    const float invd_l = (d_l == 0.f) ? 0.f : (1.f / d_l);
    const float rx_l = col_pos[3 * c_l + 0] - px;
    const float ry_l = col_pos[3 * c_l + 1] - py;
    const float rz_l = col_pos[3 * c_l + 2] - pz;

    const float b0 = att_bias[(size_t)h * E_EDGES + n * DEG + sub * 2 + 0];
    const float b1 = att_bias[(size_t)h * E_EDGES + n * DEG + sub * 2 + 1];

    float logit[DEG];
    u16* vb = &vbuf[wave * DEG * 512];
    #pragma unroll
    for (int j = 0; j < DEG; ++j) {
        const int cc = __shfl(cc_l, j);
        const u16* rowp = qkv + (size_t)cc * QKV_W + hoff;
        async16(rowp + 1024, vb + j * 512);          // v row -> LDS
        const us8 ku = *(const us8*)(rowp + 512);    // k row -> regs
        float dot = 0.f;
        #pragma unroll
        for (int i = 0; i < 8; ++i) dot += qf[i] * bf2f(ku[i]);
        dot += __shfl_xor(dot, 1, 8);
        dot += __shfl_xor(dot, 2, 8);
        dot += __shfl_xor(dot, 4, 8);
        const float invd = __shfl(invd_l, j);
        const float ang = qv0 * __shfl(rx_l, j) + qv1 * __shfl(ry_l, j)
                        + qv2 * __shfl(rz_l, j);
        const float bj = __shfl((j & 1) ? b1 : b0, j >> 1, 8);
        logit[j] = dot + bj + ang * invd;
    }

    float m = logit[0];
    #pragma unroll
    for (int j = 1; j < DEG; ++j) m = fmaxf(m, logit[j]);
    float s = 0.f;
    #pragma unroll
    for (int j = 0; j < DEG; ++j) { logit[j] = __expf(logit[j] - m); s += logit[j]; }
    const float inv_s = 1.f / s;

    __syncthreads();   // drain global_load_lds + make LDS visible

    float y[8] = {0.f, 0.f, 0.f, 0.f, 0.f, 0.f, 0.f, 0.f};
    float dx = 0.f, dy = 0.f, dz = 0.f, aid = 0.f;
    #pragma unroll
    for (int j = 0; j < DEG; ++j) {
        const float a = logit[j] * inv_s;
        const us8 vu = *(const us8*)&vb[j * 512 + hoff];
        #pragma unroll
        for (int i = 0; i < 8; ++i) y[i] += a * bf2f(vu[i]);
        const float na = a * __shfl(invd_l, j);
        dx += na * __shfl(rx_l, j);
        dy += na * __shfl(ry_l, j);
        dz += na * __shfl(rz_l, j);
        aid += na;
    }

    u16* f = feat + (size_t)n * FEAT_W + h * 68;
    ushort4 o0, o1;
    o0.x = f2bf(y[0]); o0.y = f2bf(y[1]); o0.z = f2bf(y[2]); o0.w = f2bf(y[3]);
    o1.x = f2bf(y[4]); o1.y = f2bf(y[5]); o1.z = f2bf(y[6]); o1.w = f2bf(y[7]);
    *(ushort4*)(f + sub * 8 + 0) = o0;
    *(ushort4*)(f + sub * 8 + 4) = o1;
    if (sub == 0) {
        const float nrm = sqrtf(dx * dx + dy * dy + dz * dz);
        const float rn = 1.f / fmaxf(nrm, 1e-12f);
        ushort4 ex;
        ex.x = f2bf(dx * rn); ex.y = f2bf(dy * rn);
        ex.z = f2bf(dz * rn); ex.w = f2bf(aid);
        *(ushort4*)(f + 64) = ex;
    }
}

// ---------------------------------------------------------------------------
extern "C" void kernel_launch(void* const* d_in, const int* in_sizes, int n_in,
                              void* d_out, int out_size, void* d_ws, size_t ws_size,
                              hipStream_t stream)
{
    const float* x         = (const float*)d_in[0];
    const int*   col_index = (const int*)d_in[2];
    const int*   to_col    = (const int*)d_in[3];
    const float* att_bias  = (const float*)d_in[4];
    const float* dist      = (const float*)d_in[5];
    const float* pos       = (const float*)d_in[6];
    const float* col_pos   = (const float*)d_in[7];
    const float* Wq        = (const float*)d_in[8];
    const float* Wqv       = (const float*)d_in[9];
    const float* Wk        = (const float*)d_in[10];
    const float* Wv        = (const float*)d_in[11];
    const float* Wout      = (const float*)d_in[12];
    const float* bout      = (const float*)d_in[13];
    float* out = (float*)d_out;

    // Workspace layout (bytes), total ~47.4 MB
    char* ws = (char*)d_ws;
    u16* qkv   = (u16*)(ws + 0);           // [8192,1664] bf16  27,262,976
    u16* xh    = (u16*)(ws + 27262976);    // [8192,512]  bf16   8,388,608
    u16* Bfuse = (u16*)(ws + 35651584);    // [1664,512]  bf16   1,703,936
    u16* Woth  = (u16*)(ws + 37355520);    // [512,576]   bf16     589,824
    u16* feat  = (u16*)(ws + 37945344);    // [8192,576]  bf16   9,437,184

    dim3 blk(256);

    // 0) prep: x->bf16, Bfuse (incl. qv rows), Woth
    hipLaunchKernelGGL(prep_kernel, dim3(5216), blk, 0, stream,
                       x, Wq, Wk, Wv, Wqv, Wout, xh, Bfuse, Woth);

    // 1) qkv = xh * Bfuse^T  (832 blocks, XCD-swizzled; R7-proven)
    hipLaunchKernelGGL(gemm_qkv, dim3(832), blk, 0, stream, xh, Bfuse, qkv);

    // 2) edge: wave per node, two-pass + LDS v-staging
    hipLaunchKernelGGL(edge_kernel, dim3(N_NODES / EK_WAVES), dim3(EK_WAVES * 64),
                       0, stream,
                       qkv, col_index, to_col, att_bias, dist, pos, col_pos, feat);

    // 3) out = feat * Woth^T + bout  (64x128 tiles, grid 512 = 2/CU)
    hipLaunchKernelGGL(gemm_out, dim3(512), blk, 0, stream,
                       feat, Woth, bout, out);
}

// Round 12
// 165.079 us; speedup vs baseline: 1.7661x; 1.0133x over previous
//
#include <hip/hip_runtime.h>
#include <math.h>

#define N_NODES 8192
#define D_FEAT  512
#define DEG     16
#define E_EDGES (N_NODES * DEG)
#define FEAT_W  576      // 544 used (8*(64+4)) + 32 zero-pad for K%64==0
#define FEAT_USED 544
#define OUT_W   512
#define QKV_W   1664     // 512 q | 512 k | 512 v | 24 qv | 104 pad  (13*128)

typedef unsigned short u16;
typedef __attribute__((ext_vector_type(8))) short short8;   // 8 bf16 for MFMA
typedef __attribute__((ext_vector_type(8))) unsigned short us8;
typedef __attribute__((ext_vector_type(4))) float f32x4;

// ---- bf16 helpers (RNE) ----------------------------------------------------
__device__ __forceinline__ u16 f2bf(float f) {
    union { float f; unsigned u; } c; c.f = f;
    unsigned u = c.u;
    unsigned r = u + 0x7FFFu + ((u >> 16) & 1u);
    return (u16)(r >> 16);
}
__device__ __forceinline__ float bf2f(u16 h) {
    union { unsigned u; float f; } c; c.u = ((unsigned)h) << 16;
    return c.f;
}

// ---- async global->LDS 16B (lds dest = wave-uniform base + lane*16) --------
__device__ __forceinline__ void async16(const void* g, void* l) {
    __builtin_amdgcn_global_load_lds(
        (const __attribute__((address_space(1))) void*)g,
        (__attribute__((address_space(3))) void*)l, 16, 0, 0);
}

// ---------------------------------------------------------------------------
// qkv GEMM: qkv[8192,1664] = xh[8192,512] * Bfuse[1664,512]^T, bf16 in/out.
// BK=64, 128x128 tiles, 4 waves, grid 832 = 64 Mtiles x 13 Ntiles,
// XCD-swizzled. R7/R11-proven configuration.
// ---------------------------------------------------------------------------
__global__ __launch_bounds__(256) void gemm_qkv(
    const u16* __restrict__ xh, const u16* __restrict__ Bfuse,
    u16* __restrict__ qkv)
{
    __shared__ u16 smem[128 * 64 * 2];   // 32 KB
    u16* sA = smem;
    u16* sB = smem + 128 * 64;

    const int tid = threadIdx.x;
    const int flat = blockIdx.x;
    const int xcd = flat & 7;
    const int rr  = flat >> 3;                  // 0..103
    const int bm  = (xcd + 8 * (rr / 13)) * 128;
    const int bn  = (rr % 13) * 128;

    const int wave = tid >> 6;
    const int lane = tid & 63;
    const int wr   = (wave >> 1) * 64;
    const int wc   = (wave & 1) * 64;
    const int lrow = lane & 15;
    const int quad = lane >> 4;

    f32x4 acc[4][4];
    #pragma unroll
    for (int i = 0; i < 4; ++i)
        #pragma unroll
        for (int j = 0; j < 4; ++j) {
            f32x4 z = {0.f, 0.f, 0.f, 0.f};
            acc[i][j] = z;
        }

    for (int k0 = 0; k0 < 512; k0 += 64) {
        #pragma unroll
        for (int i = 0; i < 4; ++i) {
            const int lin = i * 256 + tid;            // 1024 chunks/matrix
            const int row = lin >> 3;
            const int seg = ((lin & 7) ^ (row & 7)) << 3;
            async16(xh    + (size_t)(bm + row) * 512 + k0 + seg, sA + (lin << 3));
            async16(Bfuse + (size_t)(bn + row) * 512 + k0 + seg, sB + (lin << 3));
        }
        __syncthreads();

        #pragma unroll
        for (int ko = 0; ko < 64; ko += 32) {
            const int cbase = ko >> 3;
            short8 a_h[4], b_h[4];
            #pragma unroll
            for (int t = 0; t < 4; ++t) {
                const int ra = wr + t * 16 + lrow;
                const int rb = wc + t * 16 + lrow;
                a_h[t] = *(const short8*)&sA[ra * 64 + (((cbase + quad) ^ (ra & 7)) << 3)];
                b_h[t] = *(const short8*)&sB[rb * 64 + (((cbase + quad) ^ (rb & 7)) << 3)];
            }
            #pragma unroll
            for (int mt = 0; mt < 4; ++mt)
                #pragma unroll
                for (int nt = 0; nt < 4; ++nt)
                    acc[mt][nt] = __builtin_amdgcn_mfma_f32_16x16x32_bf16(
                        a_h[mt], b_h[nt], acc[mt][nt], 0, 0, 0);
        }
        __syncthreads();
    }

    // C/D layout: col = lane&15, row = quad*4 + r
    #pragma unroll
    for (int nt = 0; nt < 4; ++nt) {
        const int col = bn + wc + nt * 16 + lrow;
        #pragma unroll
        for (int mt = 0; mt < 4; ++mt)
            #pragma unroll
            for (int r = 0; r < 4; ++r) {
                const int row = bm + wr + mt * 16 + quad * 4 + r;
                qkv[(size_t)row * QKV_W + col] = f2bf(acc[mt][nt][r]);
            }
    }
}

// ---------------------------------------------------------------------------
// Out GEMM: out[8192,512] = feat[8192,576] * Woth[512,576]^T + bout.
// 64x128 tiles, BK=64, grid 512 = 2 blocks/CU. R11-proven.
// ---------------------------------------------------------------------------
__global__ __launch_bounds__(256) void gemm_out(
    const u16* __restrict__ feat, const u16* __restrict__ Woth,
    const float* __restrict__ bout, float* __restrict__ out)
{
    __shared__ u16 smem[64 * 64 + 128 * 64];   // 24 KB
    u16* sA = smem;
    u16* sB = smem + 64 * 64;

    const int tid = threadIdx.x;
    const int flat = blockIdx.x;
    const int xcd = flat & 7;
    const int rr  = flat >> 3;                  // 0..63
    const int bm  = (xcd + 8 * (rr / 4)) * 64;
    const int bn  = (rr % 4) * 128;

    const int wave = tid >> 6;
    const int lane = tid & 63;
    const int wr   = (wave >> 1) * 32;
    const int wc   = (wave & 1) * 64;
    const int lrow = lane & 15;
    const int quad = lane >> 4;

    f32x4 acc[2][4];
    #pragma unroll
    for (int i = 0; i < 2; ++i)
        #pragma unroll
        for (int j = 0; j < 4; ++j) {
            f32x4 z = {0.f, 0.f, 0.f, 0.f};
            acc[i][j] = z;
        }

    for (int k0 = 0; k0 < FEAT_W; k0 += 64) {
        #pragma unroll
        for (int i = 0; i < 2; ++i) {             // A: 512 chunks
            const int lin = i * 256 + tid;
            const int row = lin >> 3;
            const int seg = ((lin & 7) ^ (row & 7)) << 3;
            async16(feat + (size_t)(bm + row) * FEAT_W + k0 + seg, sA + (lin << 3));
        }
        #pragma unroll
        for (int i = 0; i < 4; ++i) {             // B: 1024 chunks
            const int lin = i * 256 + tid;
            const int row = lin >> 3;
            const int seg = ((lin & 7) ^ (row & 7)) << 3;
            async16(Woth + (size_t)(bn + row) * FEAT_W + k0 + seg, sB + (lin << 3));
        }
        __syncthreads();

        #pragma unroll
        for (int ko = 0; ko < 64; ko += 32) {
            const int cbase = ko >> 3;
            short8 a_h[2], b_h[4];
            #pragma unroll
            for (int t = 0; t < 2; ++t) {
                const int ra = wr + t * 16 + lrow;
                a_h[t] = *(const short8*)&sA[ra * 64 + (((cbase + quad) ^ (ra & 7)) << 3)];
            }
            #pragma unroll
            for (int t = 0; t < 4; ++t) {
                const int rb = wc + t * 16 + lrow;
                b_h[t] = *(const short8*)&sB[rb * 64 + (((cbase + quad) ^ (rb & 7)) << 3)];
            }
            #pragma unroll
            for (int mt = 0; mt < 2; ++mt)
                #pragma unroll
                for (int nt = 0; nt < 4; ++nt)
                    acc[mt][nt] = __builtin_amdgcn_mfma_f32_16x16x32_bf16(
                        a_h[mt], b_h[nt], acc[mt][nt], 0, 0, 0);
        }
        __syncthreads();
    }

    #pragma unroll
    for (int nt = 0; nt < 4; ++nt) {
        const int col = bn + wc + nt * 16 + lrow;
        const float bb = bout[col];
        #pragma unroll
        for (int mt = 0; mt < 2; ++mt)
            #pragma unroll
            for (int r = 0; r < 4; ++r) {
                const int row = bm + wr + mt * 16 + quad * 4 + r;
                out[(size_t)row * OUT_W + col] = acc[mt][nt][r] + bb;
            }
    }
}

// ---------------------------------------------------------------------------
// Fused prep (R7/R11-proven): block-range partition over three jobs.
// ---------------------------------------------------------------------------
__global__ __launch_bounds__(256) void prep_kernel(
    const float* __restrict__ x,
    const float* __restrict__ Wq, const float* __restrict__ Wk,
    const float* __restrict__ Wv, const float* __restrict__ Wqv,
    const float* __restrict__ Wout,
    u16* __restrict__ xh, u16* __restrict__ B, u16* __restrict__ Woth)
{
    const int b = blockIdx.x;
    const int tid = threadIdx.x;
    if (b < 4096) {
        const int i = b * 256 + tid;
        const float4 v = ((const float4*)x)[i];
        ushort4 h;
        h.x = f2bf(v.x); h.y = f2bf(v.y); h.z = f2bf(v.z); h.w = f2bf(v.w);
        ((ushort4*)xh)[i] = h;
    } else if (b < 4928) {
        const int idx = (b - 4096) * 256 + tid;      // < 212992
        const int row = idx >> 7;                    // 0..1663
        const int c4  = idx & 127;
        float4 v = make_float4(0.f, 0.f, 0.f, 0.f);
        float scale = 1.f;
        if (row < 512) {
            v = *(const float4*)(Wq + (size_t)row * 512 + c4 * 4);
            scale = 0.125f;                          // 1/sqrt(64) folded into Wq
        } else if (row < 1024) {
            v = *(const float4*)(Wk + (size_t)(row - 512) * 512 + c4 * 4);
        } else if (row < 1536) {
            v = *(const float4*)(Wv + (size_t)(row - 1024) * 512 + c4 * 4);
        } else if (row < 1560) {
            v = *(const float4*)(Wqv + (size_t)(row - 1536) * 512 + c4 * 4);
        }
        ushort4 h;
        h.x = f2bf(v.x * scale); h.y = f2bf(v.y * scale);
        h.z = f2bf(v.z * scale); h.w = f2bf(v.w * scale);
        ((ushort4*)B)[idx] = h;
    } else {
        const int i = (b - 4928) * 256 + tid;        // < 73728 exact
        const int row = i / (FEAT_W / 4);            // /144
        const int c4  = i % (FEAT_W / 4);
        float4 v = make_float4(0.f, 0.f, 0.f, 0.f);
        if (c4 < FEAT_USED / 4)
            v = *(const float4*)(Wout + (size_t)row * FEAT_USED + c4 * 4);
        ushort4 h;
        h.x = f2bf(v.x); h.y = f2bf(v.y); h.z = f2bf(v.z); h.w = f2bf(v.w);
        ((ushort4*)Woth)[i] = h;
    }
}

// ---------------------------------------------------------------------------
// Edge stage: TWO WAVES PER NODE (wave owns 8 edges, all 512 dims).
// Block = 256 threads = 4 waves = 2 nodes. lane = h*8+sub; hoff = lane*8.
// Pass 1: each wave computes 8 logits (coalesced k-row gathers).
// LDS exchange of per-head logits (64 fp32/node) -> full 16-way softmax
// replicated in both waves. Pass 2: each wave re-gathers its 8 v rows and
// accumulates partial y/dx/dy/dz/aid; wave 0 publishes partials via LDS;
// wave 1 combines and writes feat. ~6 KB LDS/block -> occupancy VGPR-bound.
// ---------------------------------------------------------------------------
__global__ __launch_bounds__(256) void edge_kernel(
    const u16* __restrict__ qkv,        // [N, 1664] bf16
    const int* __restrict__ col_index, const int* __restrict__ to_col,
    const float* __restrict__ att_bias, const float* __restrict__ dist,
    const float* __restrict__ pos, const float* __restrict__ col_pos,
    u16* __restrict__ feat)             // [N, 576] bf16 (544 used)
{
    __shared__ float sLog[2][2][8][8];  // [node][wave][head][edge]  2 KB
    __shared__ float sY[2][512];        // partial y exchange        4 KB
    __shared__ float sV[2][8][4];       // dx,dy,dz,aid per head     256 B

    const int wave4 = threadIdx.x >> 6;   // 0..3
    const int nb = wave4 >> 1;            // node within block
    const int w  = wave4 & 1;             // wave within node
    const int lane = threadIdx.x & 63;
    const int n = blockIdx.x * 2 + nb;
    const int h = lane >> 3;
    const int sub = lane & 7;
    const int hoff = lane * 8;            // == h*64 + sub*8

    const size_t qbase = (size_t)n * QKV_W;

    // q fragment (8 dims), fp32
    float qf[8];
    {
        const us8 qu = *(const us8*)(qkv + qbase + hoff);
        #pragma unroll
        for (int i = 0; i < 8; ++i) qf[i] = bf2f(qu[i]);
    }
    // qv (3 per head) via wave shuffle from the 24 bf16 at col 1536
    float qv0, qv1, qv2;
    {
        const float qvl = bf2f(qkv[qbase + 1536 + (lane < 24 ? lane : 0)]);
        qv0 = __shfl(qvl, h * 3 + 0);
        qv1 = __shfl(qvl, h * 3 + 1);
        qv2 = __shfl(qvl, h * 3 + 2);
    }
    const float px = pos[3 * n + 0], py = pos[3 * n + 1], pz = pos[3 * n + 2];

    // per-edge metadata for THIS wave's 8 edges, held in lanes 0..7
    // (all 8-lane groups hold duplicates)
    const int j8 = lane & 7;
    const int e0 = n * DEG + w * 8 + j8;
    const int c_l  = col_index[e0];
    const int cc_l = to_col[c_l];
    const float d_l = dist[e0];
    const float invd_l = (d_l == 0.f) ? 0.f : (1.f / d_l);
    const float rx_l = col_pos[3 * c_l + 0] - px;
    const float ry_l = col_pos[3 * c_l + 1] - py;
    const float rz_l = col_pos[3 * c_l + 2] - pz;

    // bias: lane (h,sub) holds bias for head h, edge w*8+sub
    const float b_own = att_bias[(size_t)h * E_EDGES + n * DEG + w * 8 + sub];

    // ---- pass 1: logits for my 8 edges -------------------------------------
    float logit[8];
    #pragma unroll
    for (int j = 0; j < 8; ++j) {
        const int cc = __shfl(cc_l, j);
        const us8 ku = *(const us8*)(qkv + (size_t)cc * QKV_W + 512 + hoff);
        float dot = 0.f;
        #pragma unroll
        for (int i = 0; i < 8; ++i) dot += qf[i] * bf2f(ku[i]);
        dot += __shfl_xor(dot, 1, 8);
        dot += __shfl_xor(dot, 2, 8);
        dot += __shfl_xor(dot, 4, 8);
        const float invd = __shfl(invd_l, j);
        const float ang = qv0 * __shfl(rx_l, j) + qv1 * __shfl(ry_l, j)
                        + qv2 * __shfl(rz_l, j);
        const float bj = __shfl(b_own, j, 8);   // lane h*8+j of this group
        logit[j] = dot + bj + ang * invd;
    }

    // ---- exchange logits, softmax over all 16 ------------------------------
    if (sub == 0) {
        #pragma unroll
        for (int j = 0; j < 8; ++j) sLog[nb][w][h][j] = logit[j];
    }
    __syncthreads();
    float lo[8];
    #pragma unroll
    for (int j = 0; j < 8; ++j) lo[j] = sLog[nb][1 - w][h][j];

    float m = logit[0];
    #pragma unroll
    for (int j = 1; j < 8; ++j) m = fmaxf(m, logit[j]);
    #pragma unroll
    for (int j = 0; j < 8; ++j) m = fmaxf(m, lo[j]);
    float s = 0.f;
    #pragma unroll
    for (int j = 0; j < 8; ++j) { logit[j] = __expf(logit[j] - m); s += logit[j]; }
    #pragma unroll
    for (int j = 0; j < 8; ++j) s += __expf(lo[j] - m);
    const float inv_s = 1.f / s;

    // ---- pass 2: weighted accumulation over my 8 edges ---------------------
    float y[8] = {0.f, 0.f, 0.f, 0.f, 0.f, 0.f, 0.f, 0.f};
    float dx = 0.f, dy = 0.f, dz = 0.f, aid = 0.f;
    #pragma unroll
    for (int j = 0; j < 8; ++j) {
        const float a = logit[j] * inv_s;
        const int cc = __shfl(cc_l, j);
        const us8 vu = *(const us8*)(qkv + (size_t)cc * QKV_W + 1024 + hoff);
        #pragma unroll
        for (int i = 0; i < 8; ++i) y[i] += a * bf2f(vu[i]);
        const float na = a * __shfl(invd_l, j);
        dx += na * __shfl(rx_l, j);      // dst_vec - src_vec == sum na*rel
        dy += na * __shfl(ry_l, j);
        dz += na * __shfl(rz_l, j);
        aid += na;
    }

    // ---- combine the two waves' partials -----------------------------------
    if (w == 0) {
        #pragma unroll
        for (int i = 0; i < 8; ++i) sY[nb][hoff + i] = y[i];
        if (sub == 0) {
            sV[nb][h][0] = dx; sV[nb][h][1] = dy;
            sV[nb][h][2] = dz; sV[nb][h][3] = aid;
        }
    }
    __syncthreads();
    if (w == 1) {
        #pragma unroll
        for (int i = 0; i < 8; ++i) y[i] += sY[nb][hoff + i];

        u16* f = feat + (size_t)n * FEAT_W + h * 68;
        ushort4 o0, o1;
        o0.x = f2bf(y[0]); o0.y = f2bf(y[1]); o0.z = f2bf(y[2]); o0.w = f2bf(y[3]);
        o1.x = f2bf(y[4]); o1.y = f2bf(y[5]); o1.z = f2bf(y[6]); o1.w = f2bf(y[7]);
        *(ushort4*)(f + sub * 8 + 0) = o0;
        *(ushort4*)(f + sub * 8 + 4) = o1;
        if (sub == 0) {
            dx += sV[nb][h][0]; dy += sV[nb][h][1];
            dz += sV[nb][h][2]; aid += sV[nb][h][3];
            const float nrm = sqrtf(dx * dx + dy * dy + dz * dz);
            const float rn = 1.f / fmaxf(nrm, 1e-12f);
            ushort4 ex;
            ex.x = f2bf(dx * rn); ex.y = f2bf(dy * rn);
            ex.z = f2bf(dz * rn); ex.w = f2bf(aid);
            *(ushort4*)(f + 64) = ex;
        }
    }
}

// ---------------------------------------------------------------------------
extern "C" void kernel_launch(void* const* d_in, const int* in_sizes, int n_in,
                              void* d_out, int out_size, void* d_ws, size_t ws_size,
                              hipStream_t stream)
{
    const float* x         = (const float*)d_in[0];
    const int*   col_index = (const int*)d_in[2];
    const int*   to_col    = (const int*)d_in[3];
    const float* att_bias  = (const float*)d_in[4];
    const float* dist      = (const float*)d_in[5];
    const float* pos       = (const float*)d_in[6];
    const float* col_pos   = (const float*)d_in[7];
    const float* Wq        = (const float*)d_in[8];
    const float* Wqv       = (const float*)d_in[9];
    const float* Wk        = (const float*)d_in[10];
    const float* Wv        = (const float*)d_in[11];
    const float* Wout      = (const float*)d_in[12];
    const float* bout      = (const float*)d_in[13];
    float* out = (float*)d_out;

    // Workspace layout (bytes), total ~47.4 MB
    char* ws = (char*)d_ws;
    u16* qkv   = (u16*)(ws + 0);           // [8192,1664] bf16  27,262,976
    u16* xh    = (u16*)(ws + 27262976);    // [8192,512]  bf16   8,388,608
    u16* Bfuse = (u16*)(ws + 35651584);    // [1664,512]  bf16   1,703,936
    u16* Woth  = (u16*)(ws + 37355520);    // [512,576]   bf16     589,824
    u16* feat  = (u16*)(ws + 37945344);    // [8192,576]  bf16   9,437,184

    dim3 blk(256);

    // 0) prep: x->bf16, Bfuse (incl. qv rows), Woth
    hipLaunchKernelGGL(prep_kernel, dim3(5216), blk, 0, stream,
                       x, Wq, Wk, Wv, Wqv, Wout, xh, Bfuse, Woth);

    // 1) qkv = xh * Bfuse^T  (832 blocks, XCD-swizzled)
    hipLaunchKernelGGL(gemm_qkv, dim3(832), blk, 0, stream, xh, Bfuse, qkv);

    // 2) edge: 2 waves per node, LDS logit/partial exchange
    hipLaunchKernelGGL(edge_kernel, dim3(N_NODES / 2), blk, 0, stream,
                       qkv, col_index, to_col, att_bias, dist, pos, col_pos, feat);

    // 3) out = feat * Woth^T + bout  (64x128 tiles, grid 512 = 2/CU)
    hipLaunchKernelGGL(gemm_out, dim3(512), blk, 0, stream,
                       feat, Woth, bout, out);
}